// Round 6
// baseline (270.393 us; speedup 1.0000x reference)
//
#include <hip/hip_runtime.h>
#include <hip/hip_bf16.h>
#include <cstdint>
#include <cstddef>

// RGCN layer, fused final stage:
//   out[n] = (sum_r h_r[n]@W[r] + x[n]@W0) / max(deg,1)
// k_fused: block = 64 nodes, 16 waves. Phase 1: round-5 gather (CSR by dst,
// wave-uniform relation switch, bf16 rows) -> 144 KB LDS A[64][1152] swizzled.
// Phase 2: 36-step MFMA GEMM A(LDS) x Wb(global, L2-resident) -> out.
// Kills the 228 MB h_cat HBM round-trip of the split version.

#define NDIM 128
#define NREL 8
#define KCAT 1152   // 9*128
#define ROWB 2304   // KCAT*2 bytes per A row

typedef __attribute__((ext_vector_type(8))) short bf16x8;
typedef __attribute__((ext_vector_type(4))) float f32x4;
typedef unsigned int uint32;

__device__ __forceinline__ short f2bf(float f){
  __hip_bfloat16 h = __float2bfloat16(f);
  return *reinterpret_cast<short*>(&h);
}
__device__ __forceinline__ float bfl(uint32 v){ return __uint_as_float(v << 16); }
__device__ __forceinline__ float bfh(uint32 v){ return __uint_as_float(v & 0xFFFF0000u); }

// ---------- K1: zero deg + detect int64/int32 (merged) ----------
__global__ void k_init(const int* ei, int* flag, int* deg, int N){
  int i = blockIdx.x * 256 + threadIdx.x;
  if (i < N) deg[i] = 0;
  if (blockIdx.x == 0 && threadIdx.x < 64){
    int v = ei[2 * threadIdx.x + 1];
    unsigned long long b = __ballot(v == 0);
    if (threadIdx.x == 0) flag[0] = (b == ~0ull) ? 1 : 0;
  }
}

// ---------- K2: x->bf16 and W->Wb bf16 transposed (merged) ----------
__global__ void k_cast(const float* __restrict__ x, uint32* __restrict__ xb, int n4,
                       int xblocks,
                       const float* __restrict__ W, const float* __restrict__ W0,
                       short* __restrict__ Wb){
  if ((int)blockIdx.x < xblocks){
    int i = blockIdx.x * 256 + threadIdx.x;
    if (i >= n4) return;
    float4 f = ((const float4*)x)[i];
    uint32 lo = ((uint32)(unsigned short)f2bf(f.x)) | (((uint32)(unsigned short)f2bf(f.y)) << 16);
    uint32 hi = ((uint32)(unsigned short)f2bf(f.z)) | (((uint32)(unsigned short)f2bf(f.w)) << 16);
    ((uint2*)xb)[i] = make_uint2(lo, hi);
  } else {
    int i = (blockIdx.x - xblocks) * 256 + threadIdx.x;
    if (i >= NDIM * KCAT) return;
    int j  = i / KCAT;
    int t  = i - j * KCAT;
    int r  = t >> 7;
    int kd = t & 127;
    float v = (r < NREL) ? W[(((size_t)r * NDIM + kd) << 7) + j] : W0[((size_t)kd << 7) + j];
    Wb[i] = f2bf(v);
  }
}

// ---------- K3: normalize edges + degree histogram ----------
__global__ void k_norm(const int* ei, const int* et, const int* __restrict__ flag,
                       int* st, int* darr, int* deg, int E){
  int e = blockIdx.x * 256 + threadIdx.x;
  if (e >= E) return;
  int is64 = flag[0];
  int s, d, t;
  if (is64){ s = ei[2*e]; d = ei[2*(E + e)]; t = et[2*e]; }
  else     { s = ei[e];   d = ei[E + e];     t = et[e];   }
  st[e]   = s | (t << 20);
  darr[e] = d;
  atomicAdd(&deg[d], 1);
}

// ---------- K4/K5/K6: exclusive scan ----------
__global__ void k_scanA(const int* deg, int* rs, int* bsum, int N){
  __shared__ int sm[256];
  int t = threadIdx.x, i = blockIdx.x * 256 + t;
  int v = (i < N) ? deg[i] : 0;
  sm[t] = v; __syncthreads();
  #pragma unroll
  for (int off = 1; off < 256; off <<= 1){
    int xv = 0; if (t >= off) xv = sm[t - off];
    __syncthreads(); sm[t] += xv; __syncthreads();
  }
  if (i < N) rs[i] = sm[t] - v;
  if (t == 255) bsum[blockIdx.x] = sm[255];
}

__global__ void k_scanB(const int* bsum, int* boff, int nblk){
  __shared__ int sm[256];
  int t = threadIdx.x;
  int v = (t < nblk) ? bsum[t] : 0;
  sm[t] = v; __syncthreads();
  #pragma unroll
  for (int off = 1; off < 256; off <<= 1){
    int xv = 0; if (t >= off) xv = sm[t - off];
    __syncthreads(); sm[t] += xv; __syncthreads();
  }
  boff[t] = sm[t] - v;
}

__global__ void k_scanC(int* rs, int* cursor, const int* boff, int N, int E){
  int i = blockIdx.x * 256 + threadIdx.x;
  if (i < N){
    int v = rs[i] + boff[blockIdx.x];
    rs[i] = v; cursor[i] = v;
  }
  if (i == 0) rs[N] = E;
}

// ---------- K7: scatter edges into CSR buckets ----------
__global__ void k_scatter(const int* st, const int* darr, int* cursor, int* esort, int E){
  int e = blockIdx.x * 256 + threadIdx.x;
  if (e >= E) return;
  int pos = atomicAdd(&cursor[darr[e]], 1);
  esort[pos] = st[e];
}

// ---------- K8: fused gather -> LDS A -> MFMA GEMM -> out ----------
__global__ __launch_bounds__(1024) void k_fused(
    const uint32* __restrict__ xb,    // [N][64] (bf16x2)
    const int* __restrict__ rs,       // [N+1]
    const int* __restrict__ esort,    // [E] src|type<<20, CSR by dst
    const short* __restrict__ wb,     // [128][1152] bf16
    float* __restrict__ out, int N)
{
  __shared__ char smem[64 * ROWB];    // 144 KB A-tile, 16B-chunk XOR swizzle
  const int tid  = threadIdx.x;
  const int lane = tid & 63;
  const int wid  = tid >> 6;          // 0..15
  const int n0   = blockIdx.x * 64;

  // ---- Phase 1: gather (round-5 structure, 4 nodes per wave) ----
  for (int i4 = 0; i4 < 4; ++i4){
    const int row  = wid * 4 + i4;
    const int node = n0 + row;
    float2 acc[NREL];
    #pragma unroll
    for (int r = 0; r < NREL; ++r){ acc[r].x = 0.f; acc[r].y = 0.f; }
    int beg = 0, end = 0;
    if (node < N){ beg = rs[node]; end = rs[node + 1]; }

    int i = beg;
    for (; i + 3 < end; i += 4){
      int p0 = esort[i], p1 = esort[i+1], p2 = esort[i+2], p3 = esort[i+3];
      uint32 v0 = xb[(size_t)(p0 & 0xFFFFF) * 64 + lane];
      uint32 v1 = xb[(size_t)(p1 & 0xFFFFF) * 64 + lane];
      uint32 v2 = xb[(size_t)(p2 & 0xFFFFF) * 64 + lane];
      uint32 v3 = xb[(size_t)(p3 & 0xFFFFF) * 64 + lane];
      switch (p0 >> 20){
        case 0: acc[0].x+=bfl(v0); acc[0].y+=bfh(v0); break; case 1: acc[1].x+=bfl(v0); acc[1].y+=bfh(v0); break;
        case 2: acc[2].x+=bfl(v0); acc[2].y+=bfh(v0); break; case 3: acc[3].x+=bfl(v0); acc[3].y+=bfh(v0); break;
        case 4: acc[4].x+=bfl(v0); acc[4].y+=bfh(v0); break; case 5: acc[5].x+=bfl(v0); acc[5].y+=bfh(v0); break;
        case 6: acc[6].x+=bfl(v0); acc[6].y+=bfh(v0); break; case 7: acc[7].x+=bfl(v0); acc[7].y+=bfh(v0); break;
      }
      switch (p1 >> 20){
        case 0: acc[0].x+=bfl(v1); acc[0].y+=bfh(v1); break; case 1: acc[1].x+=bfl(v1); acc[1].y+=bfh(v1); break;
        case 2: acc[2].x+=bfl(v1); acc[2].y+=bfh(v1); break; case 3: acc[3].x+=bfl(v1); acc[3].y+=bfh(v1); break;
        case 4: acc[4].x+=bfl(v1); acc[4].y+=bfh(v1); break; case 5: acc[5].x+=bfl(v1); acc[5].y+=bfh(v1); break;
        case 6: acc[6].x+=bfl(v1); acc[6].y+=bfh(v1); break; case 7: acc[7].x+=bfl(v1); acc[7].y+=bfh(v1); break;
      }
      switch (p2 >> 20){
        case 0: acc[0].x+=bfl(v2); acc[0].y+=bfh(v2); break; case 1: acc[1].x+=bfl(v2); acc[1].y+=bfh(v2); break;
        case 2: acc[2].x+=bfl(v2); acc[2].y+=bfh(v2); break; case 3: acc[3].x+=bfl(v2); acc[3].y+=bfh(v2); break;
        case 4: acc[4].x+=bfl(v2); acc[4].y+=bfh(v2); break; case 5: acc[5].x+=bfl(v2); acc[5].y+=bfh(v2); break;
        case 6: acc[6].x+=bfl(v2); acc[6].y+=bfh(v2); break; case 7: acc[7].x+=bfl(v2); acc[7].y+=bfh(v2); break;
      }
      switch (p3 >> 20){
        case 0: acc[0].x+=bfl(v3); acc[0].y+=bfh(v3); break; case 1: acc[1].x+=bfl(v3); acc[1].y+=bfh(v3); break;
        case 2: acc[2].x+=bfl(v3); acc[2].y+=bfh(v3); break; case 3: acc[3].x+=bfl(v3); acc[3].y+=bfh(v3); break;
        case 4: acc[4].x+=bfl(v3); acc[4].y+=bfh(v3); break; case 5: acc[5].x+=bfl(v3); acc[5].y+=bfh(v3); break;
        case 6: acc[6].x+=bfl(v3); acc[6].y+=bfh(v3); break; case 7: acc[7].x+=bfl(v3); acc[7].y+=bfh(v3); break;
      }
    }
    for (; i < end; ++i){
      int p = esort[i];
      uint32 v = xb[(size_t)(p & 0xFFFFF) * 64 + lane];
      switch (p >> 20){
        case 0: acc[0].x+=bfl(v); acc[0].y+=bfh(v); break; case 1: acc[1].x+=bfl(v); acc[1].y+=bfh(v); break;
        case 2: acc[2].x+=bfl(v); acc[2].y+=bfh(v); break; case 3: acc[3].x+=bfl(v); acc[3].y+=bfh(v); break;
        case 4: acc[4].x+=bfl(v); acc[4].y+=bfh(v); break; case 5: acc[5].x+=bfl(v); acc[5].y+=bfh(v); break;
        case 6: acc[6].x+=bfl(v); acc[6].y+=bfh(v); break; case 7: acc[7].x+=bfl(v); acc[7].y+=bfh(v); break;
      }
    }

    // write 8 relation slots + self slot into swizzled LDS row
    const int lsub = (lane & 3) * 4;
    const int chi  = lane >> 2;                  // 16B chunk within 256B slot
    char* rowp = smem + row * ROWB;
    #pragma unroll
    for (int r = 0; r < NREL; ++r){
      __hip_bfloat162 pk = __float22bfloat162_rn(make_float2(acc[r].x, acc[r].y));
      int c = r * 16 + chi;
      *(uint32*)(rowp + (((c ^ (row & 7)) << 4) + lsub)) = *reinterpret_cast<uint32*>(&pk);
    }
    uint32 sv = (node < N) ? xb[(size_t)node * 64 + lane] : 0u;
    int c8 = 128 + chi;
    *(uint32*)(rowp + (((c8 ^ (row & 7)) << 4) + lsub)) = sv;
  }
  __syncthreads();

  // ---- Phase 2: GEMM A(LDS) x Wb -> 64x128, wave tile 32 rows x 16 cols ----
  const int mi = wid >> 3;            // 0..1 : 32-row half
  const int nj = wid & 7;             // 0..7 : 16-col group
  const int lr = lane & 15;
  const int lq = lane >> 4;

  f32x4 acc2[2];
  acc2[0] = (f32x4){0.f,0.f,0.f,0.f};
  acc2[1] = (f32x4){0.f,0.f,0.f,0.f};
  const short* wrow = wb + (size_t)(nj * 16 + lr) * KCAT;

  #pragma unroll 4
  for (int ks = 0; ks < 36; ++ks){
    bf16x8 b = *(const bf16x8*)(wrow + ks * 32 + lq * 8);
    #pragma unroll
    for (int m = 0; m < 2; ++m){
      int row = mi * 32 + m * 16 + lr;
      int c   = ks * 4 + lq;
      bf16x8 a = *(const bf16x8*)(smem + row * ROWB + ((c ^ (row & 7)) << 4));
      acc2[m] = __builtin_amdgcn_mfma_f32_16x16x32_bf16(a, b, acc2[m], 0, 0, 0);
    }
  }

  // Epilogue: C/D layout col=lane&15, row=(lane>>4)*4+v; invdeg from rs.
  #pragma unroll
  for (int m = 0; m < 2; ++m){
    int rbase = n0 + mi * 32 + m * 16 + lq * 4;
    #pragma unroll
    for (int v = 0; v < 4; ++v){
      int ro = rbase + v;
      if (ro < N){
        int dg = rs[ro + 1] - rs[ro];
        float inv = 1.0f / (float)(dg > 0 ? dg : 1);
        out[(((size_t)ro) << 7) + nj * 16 + lr] = acc2[m][v] * inv;
      }
    }
  }
}

extern "C" void kernel_launch(void* const* d_in, const int* in_sizes, int n_in,
                              void* d_out, int out_size, void* d_ws, size_t ws_size,
                              hipStream_t stream){
  const float* x  = (const float*)d_in[0];
  const int*   ei = (const int*)d_in[1];
  const int*   et = (const int*)d_in[2];
  const float* W  = (const float*)d_in[4];
  const float* W0 = (const float*)d_in[5];
  float* out = (float*)d_out;

  const int N = in_sizes[0] / NDIM;   // 50000
  const int E = in_sizes[2];          // 800000

  char* ws = (char*)d_ws;
  size_t off = 0;
  auto alloc = [&](size_t bytes)->size_t{
    size_t p = off; off = (off + bytes + 255) & ~(size_t)255; return p;
  };
  size_t o_flag = alloc(4);
  size_t o_st   = alloc((size_t)E * 4);
  size_t o_d    = alloc((size_t)E * 4);
  size_t o_deg  = alloc((size_t)N * 4);
  size_t o_rs   = alloc((size_t)(N + 1) * 4);
  size_t o_cur  = alloc((size_t)N * 4);
  size_t o_bs   = alloc(256 * 4);
  size_t o_bo   = alloc(256 * 4);
  size_t o_es   = alloc((size_t)E * 4);
  size_t o_wb   = alloc((size_t)NDIM * KCAT * 2);
  size_t o_xb   = alloc((size_t)N * NDIM * 2);
  (void)ws_size;

  int*  flag   = (int*)(ws + o_flag);
  int*  st     = (int*)(ws + o_st);
  int*  darr   = (int*)(ws + o_d);
  int*  deg    = (int*)(ws + o_deg);
  int*  rs     = (int*)(ws + o_rs);
  int*  cursor = (int*)(ws + o_cur);
  int*  bsum   = (int*)(ws + o_bs);
  int*  boff   = (int*)(ws + o_bo);
  int*  esort  = (int*)(ws + o_es);
  short* Wbs   = (short*)(ws + o_wb);
  uint32* xb   = (uint32*)(ws + o_xb);

  const int nblk    = (N + 255) / 256;              // 196
  const int eblk    = (E + 255) / 256;              // 3125
  const int n4      = N * NDIM / 4;
  const int xblocks = (n4 + 255) / 256;
  const int wblocks = (NDIM * KCAT + 255) / 256;

  k_cast<<<xblocks + wblocks, 256, 0, stream>>>(x, xb, n4, xblocks, W, W0, Wbs);
  k_init<<<nblk, 256, 0, stream>>>(ei, flag, deg, N);
  k_norm<<<eblk, 256, 0, stream>>>(ei, et, flag, st, darr, deg, E);
  k_scanA<<<nblk, 256, 0, stream>>>(deg, rs, bsum, N);
  k_scanB<<<1, 256, 0, stream>>>(bsum, boff, nblk);
  k_scanC<<<nblk, 256, 0, stream>>>(rs, cursor, boff, N, E);
  k_scatter<<<eblk, 256, 0, stream>>>(st, darr, cursor, esort, E);
  k_fused<<<(N + 63) / 64, 1024, 0, stream>>>(xb, rs, esort, Wbs, out, N);
}